// Round 1
// baseline (58.525 us; speedup 1.0000x reference)
//
#include <hip/hip_runtime.h>
#include <hip/hip_bf16.h>

#define VOCAB 128
#define HIDDEN 128

// Precompute T1[v][o] = sum_h emb[v][h] * W[o][h]        + b[o]
//            T2[v][o] = sum_h emb[v][h] * W[o][128 + h]
// Grid: 128 blocks (one per vocab row v), 128 threads (one per output o).
__global__ void precompute_tables(const float* __restrict__ emb,
                                  const float* __restrict__ W,
                                  const float* __restrict__ b,
                                  float* __restrict__ T1,
                                  float* __restrict__ T2) {
    int v = blockIdx.x;
    int o = threadIdx.x;
    const float* er = emb + v * HIDDEN;        // broadcast across block
    const float* wr = W + o * (2 * HIDDEN);    // per-thread row
    float s1 = 0.f, s2 = 0.f;
#pragma unroll 8
    for (int h = 0; h < HIDDEN; ++h) {
        float ev = er[h];
        s1 += ev * wr[h];
        s2 += ev * wr[HIDDEN + h];
    }
    T1[v * HIDDEN + o] = s1 + b[o];
    T2[v * HIDDEN + o] = s2;
}

// Each edge's 128 outputs handled by 32 lanes x float4.
// out[e*128 + q*4 .. +3] = T1[z[src[e]]][q*4..] + T2[z[dst[e]]][q*4..]
__global__ __launch_bounds__(256) void edge_gather_add(
        const int* __restrict__ z,
        const int* __restrict__ src,
        const int* __restrict__ dst,
        const float* __restrict__ T1,
        const float* __restrict__ T2,
        float* __restrict__ out,
        int E) {
    int total = E * 32;
    int stride = gridDim.x * blockDim.x;
    for (int idx = blockIdx.x * blockDim.x + threadIdx.x; idx < total; idx += stride) {
        int e = idx >> 5;
        int q = idx & 31;
        int zs = z[src[e]];
        int zd = z[dst[e]];
        float4 a = *reinterpret_cast<const float4*>(T1 + zs * HIDDEN + q * 4);
        float4 c = *reinterpret_cast<const float4*>(T2 + zd * HIDDEN + q * 4);
        float4 r;
        r.x = a.x + c.x;
        r.y = a.y + c.y;
        r.z = a.z + c.z;
        r.w = a.w + c.w;
        *reinterpret_cast<float4*>(out + (size_t)e * HIDDEN + q * 4) = r;
    }
}

extern "C" void kernel_launch(void* const* d_in, const int* in_sizes, int n_in,
                              void* d_out, int out_size, void* d_ws, size_t ws_size,
                              hipStream_t stream) {
    const int*   z    = (const int*)d_in[0];          // [N_NODES]
    const int*   ei   = (const int*)d_in[1];          // [2, E] row-major
    const float* emb  = (const float*)d_in[2];        // [128, 128]
    const float* W    = (const float*)d_in[3];        // [128, 256]
    const float* b    = (const float*)d_in[4];        // [128]
    float*       out  = (float*)d_out;                // [E, 128]

    int E = in_sizes[1] / 2;
    const int* src = ei;
    const int* dst = ei + E;

    float* T1 = (float*)d_ws;                         // 128*128 f32 = 64 KB
    float* T2 = T1 + VOCAB * HIDDEN;                  // 64 KB

    precompute_tables<<<VOCAB, HIDDEN, 0, stream>>>(emb, W, b, T1, T2);

    int block = 256;
    int grid = 2048;  // grid-stride over E*32 units
    edge_gather_add<<<grid, block, 0, stream>>>(z, src, dst, T1, T2, out, E);
}